// Round 6
// baseline (53.533 us; speedup 1.0000x reference)
//
#include <hip/hip_runtime.h>
#include <hip/hip_bf16.h>
#include <climits>

typedef __bf16 bf16;
typedef __bf16 bf16x2 __attribute__((ext_vector_type(2)));
typedef __bf16 bf16x4 __attribute__((ext_vector_type(4)));
typedef __bf16 bf16x8 __attribute__((ext_vector_type(8)));
typedef float f32x4 __attribute__((ext_vector_type(4)));

#define NB 8
#define L_ 4096
#define C_ 512
#define KW 5
#define NS 8

#define GLOAD_LDS16(g, l)                                                      \
  __builtin_amdgcn_global_load_lds(                                            \
      (const __attribute__((address_space(1))) void*)(g),                      \
      (__attribute__((address_space(3))) void*)(l), 16, 0, 0)
#define GLOAD_LDS4(g, l)                                                       \
  __builtin_amdgcn_global_load_lds(                                            \
      (const __attribute__((address_space(1))) void*)(g),                      \
      (__attribute__((address_space(3))) void*)(l), 4, 0, 0)

#define PRE_BARRIER(N)                                                         \
  do {                                                                         \
    asm volatile("s_waitcnt vmcnt(" #N ") lgkmcnt(0)" ::: "memory");           \
    __builtin_amdgcn_sched_barrier(0);                                         \
    __builtin_amdgcn_s_barrier();                                              \
    __builtin_amdgcn_sched_barrier(0);                                         \
  } while (0)

// ---------------------------------------------------------------------------
// prep: w_pw fp32 -> bf16; bias2[n] = b_pw[n] + sum_k b_dw[k]*w_pw[n][k]
// ---------------------------------------------------------------------------
__global__ __launch_bounds__(256) void prep_kernel(
    const float* __restrict__ w_pw, const float* __restrict__ b_dw,
    const float* __restrict__ b_pw, bf16* __restrict__ wbf,
    float* __restrict__ bias2) {
  const int n = blockIdx.x;
  const int t = threadIdx.x;
  float2 v = *(const float2*)(w_pw + n * C_ + 2 * t);
  bf16x2 hv;
  hv[0] = (bf16)v.x;
  hv[1] = (bf16)v.y;
  *(bf16x2*)(wbf + n * C_ + 2 * t) = hv;
  float2 bb = *(const float2*)(b_dw + 2 * t);
  float s = v.x * bb.x + v.y * bb.y;
#pragma unroll
  for (int off = 32; off; off >>= 1) s += __shfl_down(s, off, 64);
  __shared__ float part[4];
  if ((t & 63) == 0) part[t >> 6] = s;
  __syncthreads();
  if (t == 0) bias2[n] = b_pw[n] + part[0] + part[1] + part[2] + part[3];
}

// ---------------------------------------------------------------------------
// conv: rolling-window segment-causal depthwise conv, pure register streaming.
// Thread owns (batch, channel-quad, 32-row chunk); window regs, no LDS.
// Segment logic is wave-uniform (all lanes of a wave share b and l).
// dwg layout: [B][L][C] bf16, NO b_dw added (folded into bias2).
// ---------------------------------------------------------------------------
__global__ __launch_bounds__(256) void conv_kernel(
    const float* __restrict__ x, const int* __restrict__ segb,
    const float* __restrict__ w_dw, bf16* __restrict__ dwg) {
  const int g = blockIdx.x * 256 + threadIdx.x;
  const int quad = g & 127;        // channel quad (4 ch)
  const int rest = g >> 7;         // 0..1023
  const int b = rest >> 7;         // 0..7
  const int chunk = rest & 127;    // 0..127
  const int l0 = chunk << 5;       // 32 rows per thread

  // taps: wt[m][i] = w_dw[quad*4+i][m]  (tap m multiplies x[l-4+m])
  float4 raw[5];
#pragma unroll
  for (int i = 0; i < 5; ++i)
    raw[i] = *(const float4*)(w_dw + quad * 20 + i * 4);
  f32x4 wt[5];
#pragma unroll
  for (int m = 0; m < 5; ++m)
#pragma unroll
    for (int i = 0; i < 4; ++i) {
      const int f = i * 5 + m;
      wt[m][i] = ((const float*)&raw[f >> 2])[f & 3];
    }

  // segment starts for this batch row (wave-uniform)
  const int* sb = segb + b * NS * 2;
  int stv[NS];
#pragma unroll
  for (int s = 0; s < NS; ++s) stv[s] = sb[2 * s];
  auto nxt = [&](int l) {
    int nn = INT_MAX;
#pragma unroll
    for (int s = 0; s < NS; ++s)
      nn = (stv[s] > l && stv[s] < nn) ? stv[s] : nn;
    return nn;
  };
  int ns = nxt(l0 - 4);

  const float* xbase = x + ((size_t)(b * L_ + l0)) * C_ + quad * 4;
  bf16* dbase = dwg + ((size_t)(b * L_ + l0)) * C_ + quad * 4;

  const f32x4 z4 = (f32x4){0.f, 0.f, 0.f, 0.f};
  f32x4 w0 = z4, w1 = z4, w2 = z4, w3 = z4;

  // warmup: l = l0-4 .. l0-1 (fills window; boundary events honored)
#pragma unroll
  for (int i = 0; i < 4; ++i) {
    const int l = l0 - 4 + i;
    f32x4 nv = z4;
    if (l >= 0) nv = *(const f32x4*)(xbase + (ptrdiff_t)(i - 4) * C_);
    if (l == ns) { w0 = z4; w1 = z4; w2 = z4; w3 = z4; ns = nxt(l); }
    w0 = w1; w1 = w2; w2 = w3; w3 = nv;
  }

  auto dorow = [&](int l, f32x4& A, f32x4& B4, f32x4& Cc, f32x4& D,
                   const f32x4& E, int off) {
    if (l == ns) { A = z4; B4 = z4; Cc = z4; D = z4; ns = nxt(l); }
    f32x4 r;
#pragma unroll
    for (int i = 0; i < 4; ++i) {
      float a = A[i] * wt[0][i];
      a = fmaf(B4[i], wt[1][i], a);
      a = fmaf(Cc[i], wt[2][i], a);
      a = fmaf(D[i], wt[3][i], a);
      a = fmaf(E[i], wt[4][i], a);
      r[i] = a;
    }
    bf16x4 h;
#pragma unroll
    for (int i = 0; i < 4; ++i) h[i] = (bf16)r[i];
    *(bf16x4*)(dbase + (size_t)off * C_) = h;
  };

#pragma unroll 1
  for (int g8 = 0; g8 < 8; ++g8) {
    const int lb = l0 + g8 * 4;
    f32x4 n0 = *(const f32x4*)(xbase + (ptrdiff_t)(g8 * 4 + 0) * C_);
    f32x4 n1 = *(const f32x4*)(xbase + (ptrdiff_t)(g8 * 4 + 1) * C_);
    f32x4 n2 = *(const f32x4*)(xbase + (ptrdiff_t)(g8 * 4 + 2) * C_);
    f32x4 n3 = *(const f32x4*)(xbase + (ptrdiff_t)(g8 * 4 + 3) * C_);
    dorow(lb + 0, w0, w1, w2, w3, n0, g8 * 4 + 0);
    dorow(lb + 1, w1, w2, w3, n0, n1, g8 * 4 + 1);
    dorow(lb + 2, w2, w3, n0, n1, n2, g8 * 4 + 2);
    dorow(lb + 3, w3, n0, n1, n2, n3, g8 * 4 + 3);
    w0 = n0; w1 = n1; w2 = n2; w3 = n3;
  }
}

// ---------------------------------------------------------------------------
// gemm: out[b,l,n] = dwg[b,l,:] . wbf[n,:] + bias2[n].
// BM=128 x BN=512, 1024 thr (16 waves, 2M x 8N), acc[4][4].
// A+B staged via global_load_lds into 3 rotating buffers; ONE barrier per
// K-step with counted vmcnt(4) (the next step's 4 loads stay in flight).
// ---------------------------------------------------------------------------
#define BMg 128
#define BNg 512
#define BKg 32
__global__ __launch_bounds__(1024) void gemm_kernel(
    const bf16* __restrict__ dwg, const bf16* __restrict__ wbf,
    const float* __restrict__ bias2, float* __restrict__ out) {
  __shared__ __align__(16) bf16 As[3][BMg * BKg];  // 8 KB each
  __shared__ __align__(16) bf16 Bs[3][BNg * BKg];  // 32 KB each

  const int t = threadIdx.x;
  const int lane = t & 63;
  const int wid = t >> 6;   // 0..15
  const int wm = wid >> 3;  // 0..1
  const int wn = wid & 7;   // 0..7

  const int b = blockIdx.x >> 5;
  const int l0 = (blockIdx.x & 31) << 7;

  // ---- A staging: 2048 4B-words/step. word q: row=q>>4, w=q&15.
  //      LDS slot chunk c=w>>2 holds global chunk c^((row>>1)&3).
  const int rA0 = t >> 4, wAi = t & 15;
  const int rA1 = 64 + (t >> 4);
  const size_t aoff0 = (size_t)(b * L_ + l0 + rA0) * C_ +
                       ((((wAi >> 2) ^ ((rA0 >> 1) & 3)) << 3) + ((wAi & 3) << 1));
  const size_t aoff1 = (size_t)(b * L_ + l0 + rA1) * C_ +
                       ((((wAi >> 2) ^ ((rA1 >> 1) & 3)) << 3) + ((wAi & 3) << 1));
  const int dA0 = wid * 128;         // bf16 elems; HW adds lane*4B
  const int dA1 = 2048 + wid * 128;

  // ---- B staging: 2048 16B-chunks/step. chunk q: n=q>>2, c=q&3.
  const int nB0 = t >> 2, cB0 = t & 3;
  const int nB1 = 256 + (t >> 2);
  const bf16* gB0 = wbf + (size_t)nB0 * C_ + (cB0 ^ ((nB0 >> 1) & 3)) * 8;
  const bf16* gB1 = wbf + (size_t)nB1 * C_ + (cB0 ^ ((nB1 >> 1) & 3)) * 8;
  const int dB0 = (t & ~63) * 8;             // elems; HW adds lane*16B
  const int dB1 = (1024 + (t & ~63)) * 8;

  // ---- frag LDS offsets (elems)
  int aOff[4], bOff[4];
#pragma unroll
  for (int mf = 0; mf < 4; ++mf) {
    const int row = wm * 64 + mf * 16 + (lane & 15);
    aOff[mf] = row * 32 + (((lane >> 4) ^ ((row >> 1) & 3)) << 3);
  }
#pragma unroll
  for (int nf = 0; nf < 4; ++nf) {
    const int nl = wn * 64 + nf * 16 + (lane & 15);
    bOff[nf] = nl * 32 + (((lane >> 4) ^ ((nl >> 1) & 3)) << 3);
  }

  f32x4 acc[4][4];
#pragma unroll
  for (int i = 0; i < 4; ++i)
#pragma unroll
    for (int j = 0; j < 4; ++j) acc[i][j] = (f32x4){0.f, 0.f, 0.f, 0.f};

  auto issueAB = [&](int kk, int p) {
    const int k0 = kk * BKg;
    bf16* a = (bf16*)As[p];
    bf16* bb = (bf16*)Bs[p];
    GLOAD_LDS4(dwg + aoff0 + k0, a + dA0);
    GLOAD_LDS4(dwg + aoff1 + k0, a + dA1);
    GLOAD_LDS16(gB0 + k0, bb + dB0);
    GLOAD_LDS16(gB1 + k0, bb + dB1);
  };

  auto mma = [&](int p) {
    const bf16* a = (const bf16*)As[p];
    const bf16* bb = (const bf16*)Bs[p];
    bf16x8 afr[4];
#pragma unroll
    for (int mf = 0; mf < 4; ++mf) afr[mf] = *(const bf16x8*)(a + aOff[mf]);
    __builtin_amdgcn_s_setprio(1);
#pragma unroll
    for (int nf = 0; nf < 4; ++nf) {
      bf16x8 bfr = *(const bf16x8*)(bb + bOff[nf]);
#pragma unroll
      for (int mf = 0; mf < 4; ++mf)
        acc[mf][nf] = __builtin_amdgcn_mfma_f32_16x16x32_bf16(
            afr[mf], bfr, acc[mf][nf], 0, 0, 0);
    }
    __builtin_amdgcn_s_setprio(0);
  };

  issueAB(0, 0);
  int pc = 0, pn = 1;
#pragma unroll 1
  for (int k = 0; k < 16; ++k) {
    if (k < 15) {
      issueAB(k + 1, pn);
      PRE_BARRIER(4);  // drain step-k's 4 loads; keep step-(k+1)'s in flight
    } else {
      PRE_BARRIER(0);
    }
    mma(pc);
    pc = (pc == 2) ? 0 : pc + 1;
    pn = (pn == 2) ? 0 : pn + 1;
  }

  // ---- epilogue
  const int col0 = wn * 64 + (lane & 15);
  float bia[4];
#pragma unroll
  for (int nf = 0; nf < 4; ++nf) bia[nf] = bias2[col0 + nf * 16];
  const int rb0 = l0 + wm * 64 + ((lane >> 4) << 2);
#pragma unroll
  for (int mf = 0; mf < 4; ++mf) {
#pragma unroll
    for (int i = 0; i < 4; ++i) {
      const int row = rb0 + mf * 16 + i;
      float* o = out + (size_t)(b * L_ + row) * C_ + col0;
#pragma unroll
      for (int nf = 0; nf < 4; ++nf) o[nf * 16] = acc[mf][nf][i] + bia[nf];
    }
  }
}

// ===========================================================================
// FALLBACK (ws too small): R4 fused kernel, unchanged.
// ===========================================================================
#define BM 128
#define BN 512
#define BK 32
#define NT 1024
__global__ __launch_bounds__(NT) void fused_dwconv_gemm(
    const float* __restrict__ x, const int* __restrict__ segb,
    const float* __restrict__ w_dw, const bf16* __restrict__ wbf,
    const float* __restrict__ bias2, float* __restrict__ out) {
  __shared__ __align__(16) bf16 Bs[2][BN * BK];
  __shared__ __align__(16) bf16 dws[2][BM][40];
  __shared__ __align__(16) float xs[2][BM + 4][BK];
  __shared__ __align__(16) float wdt[KW][C_];
  __shared__ int segst[BM];

  const int t = threadIdx.x;
  const int lane = t & 63;
  const int wid = t >> 6;
  const int wm = wid >> 2;
  const int wn = wid & 3;
  const int b = blockIdx.x >> 5;
  const int l0 = (blockIdx.x & 31) << 7;

  if (t < C_) {
#pragma unroll
    for (int d = 0; d < KW; ++d) wdt[d][t] = w_dw[t * KW + d];
  }
  if (t < BM) {
    int l = l0 + t;
    const int* sb = segb + b * NS * 2;
    int st = 0;
#pragma unroll
    for (int s = 0; s < NS; ++s) {
      int a0 = sb[2 * s], a1 = sb[2 * s + 1];
      if (l >= a0 && l < a1) st = a0;
    }
    segst[t] = st;
  }
  __syncthreads();

  const int gr = t >> 3;
  const int gc = t & 7;
  int nv = (l0 + gr) - segst[gr];
  if (nv > 4) nv = 4;
  const bool fast = __all(nv == 4);

  const float* gxp = x + (size_t)(b * L_ + l0 + gr) * C_ + gc * 4;
  const int h = wid * 2 + lane;
  const int hr = h >> 3, hc = h & 7;
  int hl = l0 - 4 + hr;
  if (hl < 0) hl = 0;
  const float* gxh = x + (size_t)(b * L_ + hl) * C_ + hc * 4;

  const int nB0 = t >> 2, cB0 = t & 3;
  const int nB1 = (NT + t) >> 2;
  const bf16* gB0 = wbf + (size_t)nB0 * C_ + (cB0 ^ ((nB0 >> 1) & 3)) * 8;
  const bf16* gB1 = wbf + (size_t)nB1 * C_ + (cB0 ^ ((nB1 >> 1) & 3)) * 8;
  const int dB0 = (t & ~63) * 8;
  const int dB1 = (NT + (t & ~63)) * 8;

  f32x4 acc[2][8];
#pragma unroll
  for (int i = 0; i < 2; ++i)
#pragma unroll
    for (int j = 0; j < 8; ++j) acc[i][j] = (f32x4){0.f, 0.f, 0.f, 0.f};

  auto issueB = [&](int kk) {
    bf16* base = (bf16*)Bs[kk & 1];
    GLOAD_LDS16(gB0 + kk * BK, base + dB0);
    GLOAD_LDS16(gB1 + kk * BK, base + dB1);
  };
  auto issueGX = [&](int kk, float4& m4, float4& h4) {
    m4 = *(const float4*)(gxp + kk * BK);
    if (lane < 2) h4 = *(const float4*)(gxh + kk * BK);
  };
  auto stageX = [&](int kk, const float4& m4, const float4& h4) {
    const int p = kk & 1;
    *(float4*)&xs[p][gr + 4][gc * 4] = m4;
    if (lane < 2) *(float4*)&xs[p][hr][hc * 4] = h4;
  };
  auto conv = [&](int kk) {
    const int p = kk & 1;
    const int k0c = kk * BK + gc * 4;
    float w[KW][4];
#pragma unroll
    for (int m = 0; m < KW; ++m) {
      float4 wv = *(const float4*)&wdt[m][k0c];
      w[m][0] = wv.x; w[m][1] = wv.y; w[m][2] = wv.z; w[m][3] = wv.w;
    }
    if (!fast) {
#pragma unroll
      for (int m = 0; m < KW; ++m)
#pragma unroll
        for (int i = 0; i < 4; ++i) w[m][i] = (4 - m <= nv) ? w[m][i] : 0.f;
    }
    f32x4 a = (f32x4){0.f, 0.f, 0.f, 0.f};
#pragma unroll
    for (int m = 0; m < KW; ++m) {
      f32x4 xv = *(const f32x4*)&xs[p][gr + m][gc * 4];
#pragma unroll
      for (int i = 0; i < 4; ++i) a[i] = fmaf(w[m][i], xv[i], a[i]);
    }
    bf16x4 hq;
#pragma unroll
    for (int i = 0; i < 4; ++i) hq[i] = (bf16)a[i];
    *(bf16x4*)&dws[p][gr][gc * 4] = hq;
  };
  auto mma = [&](int kk) {
    const int p = kk & 1;
    bf16x8 afr[2];
#pragma unroll
    for (int mf = 0; mf < 2; ++mf)
      afr[mf] = *(const bf16x8*)&dws[p][wm * 32 + mf * 16 + (lane & 15)]
                                     [(lane >> 4) * 8];
#pragma unroll
    for (int nf = 0; nf < 8; ++nf) {
      const int nl = wn * 128 + nf * 16 + (lane & 15);
      const int ph = (lane >> 4) ^ ((nl >> 1) & 3);
      bf16x8 bfr = *(const bf16x8*)&Bs[p][nl * 32 + ph * 8];
#pragma unroll
      for (int mf = 0; mf < 2; ++mf)
        acc[mf][nf] = __builtin_amdgcn_mfma_f32_16x16x32_bf16(
            afr[mf], bfr, acc[mf][nf], 0, 0, 0);
    }
  };

  float4 gm0, gm1, gh0, gh1;
  issueGX(0, gm0, gh0);
  issueGX(1, gm1, gh1);
  stageX(0, gm0, gh0);
  issueGX(2, gm0, gh0);
  PRE_BARRIER(4);
  stageX(1, gm1, gh1);
  issueB(0);
  issueGX(3, gm1, gh1);
  conv(0);
  PRE_BARRIER(2);
#pragma unroll 1
  for (int k2 = 0; k2 < 12; k2 += 2) {
    issueB(k2 + 1);
    stageX(k2 + 2, gm0, gh0);
    issueGX(k2 + 4, gm0, gh0);
    conv(k2 + 1);
    mma(k2);
    PRE_BARRIER(2);
    issueB(k2 + 2);
    stageX(k2 + 3, gm1, gh1);
    issueGX(k2 + 5, gm1, gh1);
    conv(k2 + 2);
    mma(k2 + 1);
    PRE_BARRIER(2);
  }
  issueB(13);
  stageX(14, gm0, gh0);
  conv(13);
  mma(12);
  PRE_BARRIER(0);
  issueB(14);
  stageX(15, gm1, gh1);
  conv(14);
  mma(13);
  PRE_BARRIER(0);
  issueB(15);
  conv(15);
  mma(14);
  PRE_BARRIER(0);
  mma(15);

  const int col0 = wn * 128 + (lane & 15);
  float bia[8];
#pragma unroll
  for (int nf = 0; nf < 8; ++nf) bia[nf] = bias2[col0 + nf * 16];
  const int rb0 = l0 + wm * 32 + ((lane >> 4) << 2);
#pragma unroll
  for (int mf = 0; mf < 2; ++mf) {
#pragma unroll
    for (int i = 0; i < 4; ++i) {
      const int row = rb0 + mf * 16 + i;
      float* o = out + (size_t)(b * L_ + row) * C_ + col0;
#pragma unroll
      for (int nf = 0; nf < 8; ++nf) o[nf * 16] = acc[mf][nf][i] + bia[nf];
    }
  }
}

extern "C" void kernel_launch(void* const* d_in, const int* in_sizes, int n_in,
                              void* d_out, int out_size, void* d_ws,
                              size_t ws_size, hipStream_t stream) {
  const float* x = (const float*)d_in[0];
  const int* segb = (const int*)d_in[1];
  const float* w_dw = (const float*)d_in[2];
  const float* b_dw = (const float*)d_in[3];
  const float* w_pw = (const float*)d_in[4];
  const float* b_pw = (const float*)d_in[5];
  float* out = (float*)d_out;

  bf16* wbf = (bf16*)d_ws;                             // 512 KB @ 0
  float* bias2 = (float*)((char*)d_ws + C_ * C_ * 2);  // 2 KB  @ 512K
  bf16* dwg = (bf16*)((char*)d_ws + (1 << 20));        // 32 MB @ 1M

  const size_t need = (size_t)(1 << 20) + (size_t)NB * L_ * C_ * 2;

  prep_kernel<<<C_, 256, 0, stream>>>(w_pw, b_dw, b_pw, wbf, bias2);
  if (ws_size >= need) {
    conv_kernel<<<(NB * 128 * (L_ / 32)) / 256, 256, 0, stream>>>(x, segb,
                                                                  w_dw, dwg);
    gemm_kernel<<<NB * L_ / BMg, 1024, 0, stream>>>(dwg, wbf, bias2, out);
  } else {
    fused_dwconv_gemm<<<NB * L_ / BM, NT, 0, stream>>>(x, segb, w_dw, wbf,
                                                       bias2, out);
  }
}